// Round 10
// baseline (195.458 us; speedup 1.0000x reference)
//
#include <hip/hip_runtime.h>
#include <math.h>

#define NB 2
#define NN 1024
#define DD 1024
#define NHH 16
#define HDD 64
#define BTT 20

typedef unsigned short u16;
typedef short bf16x8 __attribute__((ext_vector_type(8)));
typedef float f32x4 __attribute__((ext_vector_type(4)));

#define HMAXL 6.93147180559945f
#define LN2 0.69314718055994531f
#define C1 0.18033688011112042f   // 0.125 * log2(e)
#define TLC 0.72134752044448170f  // 0.5 * log2(e)
#define KC  0.072134752044448170f // log2(e) / 20
#define CH 520                    // padded chunk stride (1024B chunk + 16B pad) in u16

// ws offsets in floats (workspace is 256 MiB per the re-poison fill WRITE_SIZE)
#define TRAJ_OFF 0          // unnormalized w, fp32 N*N
#define TL_OFF    1048576
#define DATAB_OFF 1572864
#define WQB_OFF   2621440
#define WKB_OFF   3145728
#define WVB_OFF   3670016
#define WOB_OFF   4194304
#define QB_OFF    4718592
#define KB_OFF    5767168
#define VT_OFF    6815744
#define AOB_OFF   7864320
#define LV_OFF    8912896   // 32768 f
#define RSP_OFF   8978432   // 4*1024 f
#define EB_OFF    8982528   // E matrix, bf16 (b,h,i,j) = 32M u16 = 16M floats

__device__ __forceinline__ float b2f(u16 h) { return __uint_as_float(((unsigned)h) << 16); }
__device__ __forceinline__ u16 f2bf(float f) {
  unsigned u = __float_as_uint(f);
  return (u16)((u + 0x7fffu + ((u >> 16) & 1u)) >> 16);
}
// HW packed f32->bf16 RTNE convert (gfx950 v_cvt_pk_bf16_f32).
__device__ __forceinline__ unsigned pkbf(float a, float b) {
  unsigned r;
  asm("v_cvt_pk_bf16_f32 %0, %1, %2" : "=v"(r) : "v"(a), "v"(b));
  return r;
}
__device__ __forceinline__ void dma16(const void* g, void* l) {
  __builtin_amdgcn_global_load_lds((const __attribute__((address_space(1))) void*)g,
                                   (__attribute__((address_space(3))) void*)l, 16, 0, 0);
}

// ---------------------------------------------------------------------------
// Merged prep: blocks [0,512) = trajA (VALU/sqrt-bound, dispatched first);
// blocks [512,6656) = fp32->bf16 conversion (HBM-bound, backfills idle slots).
__global__ __launch_bounds__(256) void prep_kernel(const float* __restrict__ data,
                                                   const float* __restrict__ w0,
                                                   const float* __restrict__ w1,
                                                   const float* __restrict__ w2,
                                                   const float* __restrict__ w3,
                                                   u16* __restrict__ dd,
                                                   u16* __restrict__ d0, u16* __restrict__ d1,
                                                   u16* __restrict__ d2, u16* __restrict__ d3,
                                                   const float* __restrict__ pos,
                                                   const float* __restrict__ quat,
                                                   float* __restrict__ w,
                                                   float* __restrict__ rsp) {
  const int tid = threadIdx.x;
  const int bid = blockIdx.x;
  __shared__ float ld[8][BTT][8];
  __shared__ float wredS[4][8];
  if (bid >= 512) {
    // conversion part
    int cb = bid - 512;
    int z = cb >> 10;
    const float* s;
    u16* d;
    size_t off = 0;
    if (z < 2) { s = data; d = dd; off = (size_t)z * 1048576; }
    else if (z == 2) { s = w0; d = d0; }
    else if (z == 3) { s = w1; d = d1; }
    else if (z == 4) { s = w2; d = d2; }
    else { s = w3; d = d3; }
    size_t i = off + (size_t)((cb & 1023) * 256 + tid) * 4;
    float4 v = *(const float4*)(s + i);
    ushort4 o = {f2bf(v.x), f2bf(v.y), f2bf(v.z), f2bf(v.w)};
    *(ushort4*)(d + i) = o;
    return;
  }
  // trajA part
  const int jx = bid & 3;
  const int j = jx * 256 + tid;
  const int i0 = (bid >> 2) * 8;
  if (tid < 8 * BTT) {
    int ii = tid / BTT, bt = tid % BTT;
    const float* pp = pos + ((size_t)bt * NN + i0 + ii) * 3;
    ld[ii][bt][0] = pp[0]; ld[ii][bt][1] = pp[1]; ld[ii][bt][2] = pp[2];
    *(float4*)&ld[ii][bt][4] = *(const float4*)(quat + ((size_t)bt * NN + i0 + ii) * 4);
  }
  __syncthreads();
  float acc[8] = {};
  for (int bt = 0; bt < BTT; ++bt) {
    const float* pj = pos + ((size_t)bt * NN + j) * 3;
    float pjx = pj[0], pjy = pj[1], pjz = pj[2];
    float4 qj = *(const float4*)(quat + ((size_t)bt * NN + j) * 4);
#pragma unroll
    for (int ii = 0; ii < 8; ++ii) {
      float4 pi = *(const float4*)&ld[ii][bt][0];
      float4 qi = *(const float4*)&ld[ii][bt][4];
      float dx = pi.x - pjx, dy = pi.y - pjy, dz = pi.z - pjz;
      float d2 = fmaf(dz, dz, fmaf(dy, dy, dx * dx));
      float dot = fmaf(qi.w, qj.w, fmaf(qi.z, qj.z, fmaf(qi.y, qj.y, qi.x * qj.x)));
      float tq = fmaf(-2.f, fabsf(dot), 2.f);
      acc[ii] += sqrtf(d2) + sqrtf(fmaxf(tq, 0.f));
    }
  }
  const int wv = tid >> 6;
#pragma unroll
  for (int ii = 0; ii < 8; ++ii) {
    float v = exp2f(-acc[ii] * KC);
    w[(size_t)(i0 + ii) * NN + j] = v;
    float s = v;
#pragma unroll
    for (int off = 1; off < 64; off <<= 1) s += __shfl_xor(s, off, 64);
    if ((tid & 63) == 0) wredS[wv][ii] = s;
  }
  __syncthreads();
  if (tid < 8)
    rsp[jx * 1024 + i0 + tid] = wredS[0][tid] + wredS[1][tid] + wredS[2][tid] + wredS[3][tid];
}

// ---------------------------------------------------------------------------
// blocks [0,256)   = trajB; blocks [256,512) = merged Q+K GEMM;
// blocks [512,768) = V GEMM. (R15 structure, validated: BK=64 + T2 swizzle.)
__global__ __launch_bounds__(256, 3) void qkv_trajB_kernel(const u16* __restrict__ Ab,
                                                        const u16* __restrict__ Wq,
                                                        const u16* __restrict__ Wk,
                                                        const u16* __restrict__ Wv,
                                                        const float* __restrict__ bq,
                                                        const float* __restrict__ bk,
                                                        const float* __restrict__ bv,
                                                        u16* __restrict__ Qb,
                                                        u16* __restrict__ Kb,
                                                        u16* __restrict__ VtT,
                                                        const float* __restrict__ wtr,
                                                        const float* __restrict__ rsp,
                                                        u16* __restrict__ tl) {
  const int tid = threadIdx.x;
  __shared__ __align__(16) u16 As[128 * 64];
  __shared__ __align__(16) u16 Bs[2][64 * 64];
  if (blockIdx.x < 256) {
    int base = blockIdx.x * 4;
#pragma unroll
    for (int r = 0; r < 4; ++r) {
      int i = base + r;
      float inv = TLC / (rsp[i] + rsp[1024 + i] + rsp[2048 + i] + rsp[3072 + i]);
      float4 w4 = *(const float4*)(wtr + (size_t)i * NN + tid * 4);
      ushort4 o = {f2bf(w4.x * inv), f2bf(w4.y * inv), f2bf(w4.z * inv), f2bf(w4.w * inv)};
      *(ushort4*)(tl + (size_t)i * NN + tid * 4) = o;
    }
    return;
  }
  const int bid = blockIdx.x - 256;
  const bool isQK = bid < 256;
  const int rem = bid & 255;
  const int bn = (rem & 15) << 6;          // 16 n-tiles of 64
  const int bm = (rem >> 4) << 7;          // 16 m-tiles of 128
  const int w = tid >> 6, l = tid & 63, g = l >> 4, ln = l & 15;
  const int lr = l >> 3;                   // row-in-chunk (= row&7 of staged row)
  const int sgc = ((l & 7) ^ lr) * 8;      // pre-swizzled global col slot (u16)
  const u16* ApA = Ab + (size_t)(bm + w * 32 + lr) * DD + sgc;
  u16* dAc = As + (w * 4) * 512;
  const int mw = (w & 1) * 64, nw = (w >> 1) * 32;
  const int lx = ln & 7;                   // row&7 for fragment reads
  f32x4 zero4 = {0.f, 0.f, 0.f, 0.f};
  if (isQK) {
    const u16* BqP = Wq + (size_t)(bn + w * 16 + lr) * DD + sgc;
    const u16* BkP = Wk + (size_t)(bn + w * 16 + lr) * DD + sgc;
    u16* dBq = Bs[0] + (w * 2) * 512;
    u16* dBk = Bs[1] + (w * 2) * 512;
    f32x4 acc[2][4][2];
#pragma unroll
    for (int z = 0; z < 2; ++z)
#pragma unroll
      for (int mt = 0; mt < 4; ++mt)
#pragma unroll
        for (int nt = 0; nt < 2; ++nt) acc[z][mt][nt] = zero4;
    for (int k0 = 0; k0 < DD; k0 += 64) {
      __syncthreads();
#pragma unroll
      for (int d = 0; d < 4; ++d)
        dma16(ApA + (size_t)(d * 8) * DD + k0, dAc + d * 512);
#pragma unroll
      for (int d = 0; d < 2; ++d) {
        dma16(BqP + (size_t)(d * 8) * DD + k0, dBq + d * 512);
        dma16(BkP + (size_t)(d * 8) * DD + k0, dBk + d * 512);
      }
      __syncthreads();
#pragma unroll
      for (int kc = 0; kc < 2; ++kc) {
        const int so = ((kc * 4 + g) ^ lx) * 8;
        bf16x8 afr[4], bqf[2], bkf[2];
#pragma unroll
        for (int nt = 0; nt < 2; ++nt) {
          int off = (nw + nt * 16 + ln) * 64 + so;
          bqf[nt] = *(const bf16x8*)&Bs[0][off];
          bkf[nt] = *(const bf16x8*)&Bs[1][off];
        }
#pragma unroll
        for (int mt = 0; mt < 4; ++mt)
          afr[mt] = *(const bf16x8*)&As[(mw + mt * 16 + ln) * 64 + so];
#pragma unroll
        for (int mt = 0; mt < 4; ++mt)
#pragma unroll
          for (int nt = 0; nt < 2; ++nt) {
            acc[0][mt][nt] = __builtin_amdgcn_mfma_f32_16x16x32_bf16(afr[mt], bqf[nt], acc[0][mt][nt], 0, 0, 0);
            acc[1][mt][nt] = __builtin_amdgcn_mfma_f32_16x16x32_bf16(afr[mt], bkf[nt], acc[1][mt][nt], 0, 0, 0);
          }
      }
    }
#pragma unroll
    for (int z = 0; z < 2; ++z) {
      u16* outp = z == 0 ? Qb : Kb;
      const float* bias = z == 0 ? bq : bk;
#pragma unroll
      for (int nt = 0; nt < 2; ++nt) {
        int n = bn + nw + nt * 16 + ln;
        float bb = bias[n];
#pragma unroll
        for (int mt = 0; mt < 4; ++mt) {
#pragma unroll
          for (int r = 0; r < 4; ++r) {
            int m = bm + mw + mt * 16 + g * 4 + r;
            outp[(size_t)m * DD + n] = f2bf(acc[z][mt][nt][r] + bb);
          }
        }
      }
    }
    return;
  }
  // V path
  const u16* BvP = Wv + (size_t)(bn + w * 16 + lr) * DD + sgc;
  u16* dBv = Bs[0] + (w * 2) * 512;
  f32x4 acc[4][2];
#pragma unroll
  for (int mt = 0; mt < 4; ++mt)
#pragma unroll
    for (int nt = 0; nt < 2; ++nt) acc[mt][nt] = zero4;
  for (int k0 = 0; k0 < DD; k0 += 64) {
    __syncthreads();
#pragma unroll
    for (int d = 0; d < 4; ++d)
      dma16(ApA + (size_t)(d * 8) * DD + k0, dAc + d * 512);
#pragma unroll
    for (int d = 0; d < 2; ++d)
      dma16(BvP + (size_t)(d * 8) * DD + k0, dBv + d * 512);
    __syncthreads();
#pragma unroll
    for (int kc = 0; kc < 2; ++kc) {
      const int so = ((kc * 4 + g) ^ lx) * 8;
      bf16x8 bfr[2], afr[4];
#pragma unroll
      for (int nt = 0; nt < 2; ++nt)
        bfr[nt] = *(const bf16x8*)&Bs[0][(nw + nt * 16 + ln) * 64 + so];
#pragma unroll
      for (int mt = 0; mt < 4; ++mt)
        afr[mt] = *(const bf16x8*)&As[(mw + mt * 16 + ln) * 64 + so];
#pragma unroll
      for (int mt = 0; mt < 4; ++mt)
#pragma unroll
        for (int nt = 0; nt < 2; ++nt)
          acc[mt][nt] = __builtin_amdgcn_mfma_f32_16x16x32_bf16(afr[mt], bfr[nt], acc[mt][nt], 0, 0, 0);
    }
  }
#pragma unroll
  for (int nt = 0; nt < 2; ++nt) {
    int n = bn + nw + nt * 16 + ln;
    float bb = bv[n];
    int row = (((bm >> 10) << 4) + (n >> 6)) * 64 + (n & 63);
#pragma unroll
    for (int mt = 0; mt < 4; ++mt) {
      int tok = (bm & 1023) + mw + mt * 16 + g * 4;
      ushort4 pk = {f2bf(acc[mt][nt][0] + bb), f2bf(acc[mt][nt][1] + bb),
                    f2bf(acc[mt][nt][2] + bb), f2bf(acc[mt][nt][3] + bb)};
      *(ushort4*)(VtT + (size_t)row * NN + tok) = pk;
    }
  }
}

// ---------------------------------------------------------------------------
// MFMA flash attention + E materialization. R18: R15-mechanism applied to att
// -- stage 256 j per iteration (Ks[4]/Vts[4]) so the j-loop runs 4 iterations
// with 8 barriers total instead of 8 iterations/16 barriers (same 64 dma16).
// LDS would be 84 KB (-> 1 block/CU, fatal), so Qs is UNIONED into Pt (Q
// staging is consumed once at t==0; Pt only written during compute). The one
// cross-wave hazard (wave A's first Pt write vs wave B's qf read) is closed by
// a single extra __syncthreads() at t==0. LDS 76 KB -> 2 blocks/CU preserved.
// XCD swizzle kept (R17). j-order of compute unchanged -> bit-identical.
__global__ __launch_bounds__(256) void att_kernel(const u16* __restrict__ Qb,
                                                  const u16* __restrict__ Kb,
                                                  const u16* __restrict__ VtT,
                                                  const u16* __restrict__ tl,
                                                  u16* __restrict__ AOb,
                                                  float* __restrict__ Lv,
                                                  u16* __restrict__ Eb) {
  const int tid = threadIdx.x;
  // XCD swizzle: 512 blocks, 512%8==0 -> clean bijection (m204).
  const int wk = (blockIdx.x & 7) * 64 + (blockIdx.x >> 3);
  const int bh = wk >> 4;           // 4 consecutive heads per XCD chunk
  const int b = bh >> 4, h = bh & 15;
  const int i0 = (wk & 15) << 6;
  const int w = tid >> 6, l = tid & 63, g = l >> 4, ln = l & 15;
  const int wi0 = w * 16;
  __shared__ __align__(16) u16 Ks[4][8 * CH];
  __shared__ __align__(16) u16 Vts[4][8 * CH];
  __shared__ __align__(16) u16 Pt[64 * 72];   // first 8320 B double as Qs
  __shared__ float lsc[64];
  u16* Qs = Pt;                               // union (see header comment)
  const int c0 = 2 * w, c1 = 2 * w + 1;
  const int rr = 8 * (l >> 3);
  const int dcol = (l & 7) * 8;
  dma16(Qb + ((size_t)(b * NN) + i0 + c0 + rr) * DD + h * HDD + dcol, Qs + c0 * CH);
  dma16(Qb + ((size_t)(b * NN) + i0 + c1 + rr) * DD + h * HDD + dcol, Qs + c1 * CH);
  const int ig = i0 + wi0 + ln;
  u16* Erow = Eb + ((size_t)bh * NN + ig) * NN;   // E row for this thread's i
  const int lnlo = (ln & 7) * CH;
  const int lnhi = (ln >> 3) * 64;
  f32x4 zero4 = {0.f, 0.f, 0.f, 0.f};
  f32x4 oacc[4];
#pragma unroll
  for (int nt = 0; nt < 4; ++nt) oacc[nt] = zero4;
  float lacc = 0.f;
  bf16x8 qf[2];
  for (int t = 0; t < 4; ++t) {
    const int j0 = t << 8;                    // 256 j per iteration
    __syncthreads();                          // bar-A: LDS free + E-stores drained
#pragma unroll
    for (int u = 0; u < 4; ++u) {
      int jb = j0 + u * 64;
      dma16(Kb + ((size_t)(b * NN) + jb + c0 + rr) * DD + h * HDD + dcol, Ks[u] + c0 * CH);
      dma16(Kb + ((size_t)(b * NN) + jb + c1 + rr) * DD + h * HDD + dcol, Ks[u] + c1 * CH);
      dma16(VtT + ((size_t)(bh * 64) + c0 + rr) * NN + jb + dcol, Vts[u] + c0 * CH);
      dma16(VtT + ((size_t)(bh * 64) + c1 + rr) * NN + jb + dcol, Vts[u] + c1 * CH);
    }
    ushort4 tlv[4][4];
#pragma unroll
    for (int u = 0; u < 4; ++u)
#pragma unroll
      for (int jt = 0; jt < 4; ++jt)
        tlv[u][jt] = *(const ushort4*)(tl + (size_t)ig * NN + j0 + u * 64 + jt * 16 + g * 4);
    __syncthreads();                          // bar-B: staging (+Q at t==0) done
    if (t == 0) {
      qf[0] = *(const bf16x8*)&Qs[lnlo + (2 * w) * 64 + lnhi + g * 8];
      qf[1] = *(const bf16x8*)&Qs[lnlo + (2 * w) * 64 + lnhi + 32 + g * 8];
      __syncthreads();                        // all qf reads before any Pt write
    }
#pragma unroll
    for (int u = 0; u < 4; ++u) {
      f32x4 sacc[4];
      __builtin_amdgcn_s_setprio(1);
#pragma unroll
      for (int jt = 0; jt < 4; ++jt) {
        sacc[jt] = zero4;
#pragma unroll
        for (int kc = 0; kc < 2; ++kc) {
          bf16x8 af = *(const bf16x8*)&Ks[u][lnlo + (2 * jt) * 64 + lnhi + kc * 32 + g * 8];
          sacc[jt] = __builtin_amdgcn_mfma_f32_16x16x32_bf16(af, qf[kc], sacc[jt], 0, 0, 0);
        }
      }
      __builtin_amdgcn_s_setprio(0);
#pragma unroll
      for (int jt = 0; jt < 4; ++jt) {
        float e0 = exp2f(sacc[jt][0] * C1 + b2f(tlv[u][jt].x));
        float e1 = exp2f(sacc[jt][1] * C1 + b2f(tlv[u][jt].y));
        float e2 = exp2f(sacc[jt][2] * C1 + b2f(tlv[u][jt].z));
        float e3 = exp2f(sacc[jt][3] * C1 + b2f(tlv[u][jt].w));
        lacc += (e0 + e1) + (e2 + e3);
        uint2 pk = {pkbf(e0, e1), pkbf(e2, e3)};
        *(uint2*)(Pt + (wi0 + ln) * 72 + jt * 16 + g * 4) = pk;
        *(uint2*)(Erow + j0 + u * 64 + jt * 16 + g * 4) = pk;   // materialize E
      }
      bf16x8 pf[2];
      pf[0] = *(const bf16x8*)&Pt[(wi0 + ln) * 72 + g * 8];
      pf[1] = *(const bf16x8*)&Pt[(wi0 + ln) * 72 + 32 + g * 8];
      __builtin_amdgcn_s_setprio(1);
#pragma unroll
      for (int nt = 0; nt < 4; ++nt) {
#pragma unroll
        for (int kc = 0; kc < 2; ++kc) {
          bf16x8 vf = *(const bf16x8*)&Vts[u][lnlo + (2 * nt) * 64 + lnhi + kc * 32 + g * 8];
          oacc[nt] = __builtin_amdgcn_mfma_f32_16x16x32_bf16(pf[kc], vf, oacc[nt], 0, 0, 0);
        }
      }
      __builtin_amdgcn_s_setprio(0);
    }
  }
  lacc += __shfl_xor(lacc, 16, 64);
  lacc += __shfl_xor(lacc, 32, 64);
  if (g == 0) {
    Lv[(size_t)bh * NN + i0 + wi0 + ln] = lacc;
    lsc[wi0 + ln] = 1.f / lacc;
  }
  __syncthreads();
#pragma unroll
  for (int nt = 0; nt < 4; ++nt) {
    int d = nt * 16 + ln;
#pragma unroll
    for (int r = 0; r < 4; ++r) {
      int i = wi0 + g * 4 + r;
      float v = oacc[nt][r] * lsc[i];
      AOb[((size_t)(b * NN) + i0 + i) * DD + h * HDD + d] = f2bf(v);
    }
  }
}

// ---------------------------------------------------------------------------
// Fused final stage: blocks [0,256) = output projection GEMM (BK=64 +
// swizzle, R15-validated); blocks [256,768) = streaming entropy + certainty.
__global__ __launch_bounds__(256) void gemmo_ent_kernel(const u16* __restrict__ Ab,
                                                        const u16* __restrict__ Wb,
                                                        const float* __restrict__ bias,
                                                        float* __restrict__ C,
                                                        const u16* __restrict__ Eb,
                                                        const float* __restrict__ Lv,
                                                        const float* __restrict__ cert,
                                                        float* __restrict__ outc) {
  const int tid = threadIdx.x;
  __shared__ __align__(16) u16 As[128 * 64];
  __shared__ __align__(16) u16 Bs[64 * 64];
  __shared__ float linvS[4][16];
  __shared__ float redS[4][4];   // [wave][row]
  if (blockIdx.x >= 256) {
    const int e = blockIdx.x - 256;       // [0,512)
    const int b = e >> 8;
    const int ib4 = (e & 255) << 2;       // 4 rows per block
    if (tid < 64) {
      int r = tid >> 4, h = tid & 15;
      linvS[r][h] = 1.f / Lv[((size_t)(b * 16 + h)) * NN + ib4 + r];
    }
    __syncthreads();
    const int jb = tid * 4;               // 256 threads cover 1024 j
    float A[4];
#pragma unroll
    for (int r = 0; r < 4; ++r) {
      float s0 = 0.f, s1 = 0.f, s2 = 0.f, s3 = 0.f;
#pragma unroll
      for (int h = 0; h < 16; ++h) {
        ushort4 v = *(const ushort4*)(Eb + (((size_t)(b * 16 + h)) * NN + ib4 + r) * NN + jb);
        float li = linvS[r][h];
        s0 = fmaf(b2f(v.x), li, s0); s1 = fmaf(b2f(v.y), li, s1);
        s2 = fmaf(b2f(v.z), li, s2); s3 = fmaf(b2f(v.w), li, s3);
      }
      float p0 = fmaxf(s0 * (1.f / NHH), 1e-10f);
      float p1 = fmaxf(s1 * (1.f / NHH), 1e-10f);
      float p2 = fmaxf(s2 * (1.f / NHH), 1e-10f);
      float p3 = fmaxf(s3 * (1.f / NHH), 1e-10f);
      A[r] = p0 * __log2f(p0) + p1 * __log2f(p1) + p2 * __log2f(p2) + p3 * __log2f(p3);
    }
#pragma unroll
    for (int r = 0; r < 4; ++r)
#pragma unroll
      for (int off = 1; off < 64; off <<= 1) A[r] += __shfl_xor(A[r], off, 64);
    const int wv = tid >> 6;
    if ((tid & 63) == 0) {
#pragma unroll
      for (int r = 0; r < 4; ++r) redS[wv][r] = A[r];
    }
    __syncthreads();
    if (tid < 4) {
      float H = -LN2 * (redS[0][tid] + redS[1][tid] + redS[2][tid] + redS[3][tid]);
      int idx = b * NN + ib4 + tid;
      float sg = 1.f / (1.f + expf(H - HMAXL));
      outc[idx] = fmaxf(cert[idx], sg);
    }
    return;
  }
  const int bn = (blockIdx.x & 15) << 6;   // 16 n-tiles of 64
  const int bm = (blockIdx.x >> 4) << 7;   // 16 m-tiles of 128
  const int w = tid >> 6, l = tid & 63, g = l >> 4, ln = l & 15;
  const int lr = l >> 3;
  const int sgc = ((l & 7) ^ lr) * 8;
  const u16* ApA = Ab + (size_t)(bm + w * 32 + lr) * DD + sgc;
  const u16* BoP = Wb + (size_t)(bn + w * 16 + lr) * DD + sgc;
  u16* dAc = As + (w * 4) * 512;
  u16* dBo = Bs + (w * 2) * 512;
  const int mw = (w & 1) * 64, nw = (w >> 1) * 32;
  const int lx = ln & 7;
  f32x4 zero4 = {0.f, 0.f, 0.f, 0.f};
  f32x4 acc[4][2];
#pragma unroll
  for (int mt = 0; mt < 4; ++mt)
#pragma unroll
    for (int nt = 0; nt < 2; ++nt) acc[mt][nt] = zero4;
  for (int k0 = 0; k0 < DD; k0 += 64) {
    __syncthreads();
#pragma unroll
    for (int d = 0; d < 4; ++d)
      dma16(ApA + (size_t)(d * 8) * DD + k0, dAc + d * 512);
#pragma unroll
    for (int d = 0; d < 2; ++d)
      dma16(BoP + (size_t)(d * 8) * DD + k0, dBo + d * 512);
    __syncthreads();
#pragma unroll
    for (int kc = 0; kc < 2; ++kc) {
      const int so = ((kc * 4 + g) ^ lx) * 8;
      bf16x8 bfr[2], afr[4];
#pragma unroll
      for (int nt = 0; nt < 2; ++nt)
        bfr[nt] = *(const bf16x8*)&Bs[(nw + nt * 16 + ln) * 64 + so];
#pragma unroll
      for (int mt = 0; mt < 4; ++mt)
        afr[mt] = *(const bf16x8*)&As[(mw + mt * 16 + ln) * 64 + so];
#pragma unroll
      for (int mt = 0; mt < 4; ++mt)
#pragma unroll
        for (int nt = 0; nt < 2; ++nt)
          acc[mt][nt] = __builtin_amdgcn_mfma_f32_16x16x32_bf16(afr[mt], bfr[nt], acc[mt][nt], 0, 0, 0);
    }
  }
#pragma unroll
  for (int nt = 0; nt < 2; ++nt) {
    int n = bn + nw + nt * 16 + ln;
    float bb = bias[n];
#pragma unroll
    for (int mt = 0; mt < 4; ++mt) {
#pragma unroll
      for (int r = 0; r < 4; ++r) {
        int m = bm + mw + mt * 16 + g * 4 + r;
        C[(size_t)m * DD + n] = acc[mt][nt][r] + bb;
      }
    }
  }
}

// ---------------------------------------------------------------------------
extern "C" void kernel_launch(void* const* d_in, const int* in_sizes, int n_in,
                              void* d_out, int out_size, void* d_ws, size_t ws_size,
                              hipStream_t stream) {
  const float* data      = (const float*)d_in[0];
  const float* traj_pos  = (const float*)d_in[1];
  const float* traj_quat = (const float*)d_in[2];
  const float* certainty = (const float*)d_in[3];
  const float* Wq = (const float*)d_in[4];
  const float* bq = (const float*)d_in[5];
  const float* Wk = (const float*)d_in[6];
  const float* bk = (const float*)d_in[7];
  const float* Wv = (const float*)d_in[8];
  const float* bv = (const float*)d_in[9];
  const float* Wo = (const float*)d_in[10];
  const float* bo = (const float*)d_in[11];

  float* ws = (float*)d_ws;
  float* wtr  = ws + TRAJ_OFF;
  u16* tl    = (u16*)(ws + TL_OFF);
  u16* datab = (u16*)(ws + DATAB_OFF);
  u16* wqb   = (u16*)(ws + WQB_OFF);
  u16* wkb   = (u16*)(ws + WKB_OFF);
  u16* wvb   = (u16*)(ws + WVB_OFF);
  u16* wob   = (u16*)(ws + WOB_OFF);
  u16* Qb    = (u16*)(ws + QB_OFF);
  u16* Kb    = (u16*)(ws + KB_OFF);
  u16* VtT   = (u16*)(ws + VT_OFF);
  u16* AOb   = (u16*)(ws + AOB_OFF);
  float* Lv   = ws + LV_OFF;
  float* rsp  = ws + RSP_OFF;
  u16* Eb    = (u16*)(ws + EB_OFF);
  float* out  = (float*)d_out;
  float* outc = out + (size_t)NB * NN * DD;

  prep_kernel<<<6656, 256, 0, stream>>>(data, Wq, Wk, Wv, Wo,
                                        datab, wqb, wkb, wvb, wob,
                                        traj_pos, traj_quat, wtr, rsp);
  qkv_trajB_kernel<<<768, 256, 0, stream>>>(datab, wqb, wkb, wvb, bq, bk, bv,
                                            Qb, Kb, VtT, wtr, rsp, tl);
  att_kernel<<<512, 256, 0, stream>>>(Qb, Kb, VtT, tl, AOb, Lv, Eb);
  gemmo_ent_kernel<<<768, 256, 0, stream>>>(AOb, wob, bo, out, Eb, Lv, certainty, outc);
}

// Round 11
// 194.027 us; speedup vs baseline: 1.0074x; 1.0074x over previous
//
#include <hip/hip_runtime.h>
#include <math.h>

#define NB 2
#define NN 1024
#define DD 1024
#define NHH 16
#define HDD 64
#define BTT 20

typedef unsigned short u16;
typedef short bf16x8 __attribute__((ext_vector_type(8)));
typedef float f32x4 __attribute__((ext_vector_type(4)));

#define HMAXL 6.93147180559945f
#define LN2 0.69314718055994531f
#define C1 0.18033688011112042f   // 0.125 * log2(e)
#define TLC 0.72134752044448170f  // 0.5 * log2(e)
#define KC  0.072134752044448170f // log2(e) / 20
#define CH 520                    // padded chunk stride (1024B chunk + 16B pad) in u16

// ws offsets in floats (workspace is 256 MiB per the re-poison fill WRITE_SIZE)
#define TRAJ_OFF 0          // unnormalized w, fp32 N*N
#define TL_OFF    1048576
#define DATAB_OFF 1572864
#define WQB_OFF   2621440
#define WKB_OFF   3145728
#define WVB_OFF   3670016
#define WOB_OFF   4194304
#define QB_OFF    4718592
#define KB_OFF    5767168
#define VT_OFF    6815744
#define AOB_OFF   7864320
#define LV_OFF    8912896   // 32768 f
#define RSP_OFF   8978432   // 4*1024 f
#define EB_OFF    8982528   // E matrix, bf16 (b,h,i,j) = 32M u16 = 16M floats

__device__ __forceinline__ float b2f(u16 h) { return __uint_as_float(((unsigned)h) << 16); }
__device__ __forceinline__ u16 f2bf(float f) {
  unsigned u = __float_as_uint(f);
  return (u16)((u + 0x7fffu + ((u >> 16) & 1u)) >> 16);
}
// HW packed f32->bf16 RTNE convert (gfx950 v_cvt_pk_bf16_f32).
__device__ __forceinline__ unsigned pkbf(float a, float b) {
  unsigned r;
  asm("v_cvt_pk_bf16_f32 %0, %1, %2" : "=v"(r) : "v"(a), "v"(b));
  return r;
}
__device__ __forceinline__ void dma16(const void* g, void* l) {
  __builtin_amdgcn_global_load_lds((const __attribute__((address_space(1))) void*)g,
                                   (__attribute__((address_space(3))) void*)l, 16, 0, 0);
}

// ---------------------------------------------------------------------------
// Merged prep: blocks [0,512) = trajA (VALU/sqrt-bound, dispatched first);
// blocks [512,6656) = fp32->bf16 conversion (HBM-bound, backfills idle slots).
__global__ __launch_bounds__(256) void prep_kernel(const float* __restrict__ data,
                                                   const float* __restrict__ w0,
                                                   const float* __restrict__ w1,
                                                   const float* __restrict__ w2,
                                                   const float* __restrict__ w3,
                                                   u16* __restrict__ dd,
                                                   u16* __restrict__ d0, u16* __restrict__ d1,
                                                   u16* __restrict__ d2, u16* __restrict__ d3,
                                                   const float* __restrict__ pos,
                                                   const float* __restrict__ quat,
                                                   float* __restrict__ w,
                                                   float* __restrict__ rsp) {
  const int tid = threadIdx.x;
  const int bid = blockIdx.x;
  __shared__ float ld[8][BTT][8];
  __shared__ float wredS[4][8];
  if (bid >= 512) {
    // conversion part
    int cb = bid - 512;
    int z = cb >> 10;
    const float* s;
    u16* d;
    size_t off = 0;
    if (z < 2) { s = data; d = dd; off = (size_t)z * 1048576; }
    else if (z == 2) { s = w0; d = d0; }
    else if (z == 3) { s = w1; d = d1; }
    else if (z == 4) { s = w2; d = d2; }
    else { s = w3; d = d3; }
    size_t i = off + (size_t)((cb & 1023) * 256 + tid) * 4;
    float4 v = *(const float4*)(s + i);
    ushort4 o = {f2bf(v.x), f2bf(v.y), f2bf(v.z), f2bf(v.w)};
    *(ushort4*)(d + i) = o;
    return;
  }
  // trajA part
  const int jx = bid & 3;
  const int j = jx * 256 + tid;
  const int i0 = (bid >> 2) * 8;
  if (tid < 8 * BTT) {
    int ii = tid / BTT, bt = tid % BTT;
    const float* pp = pos + ((size_t)bt * NN + i0 + ii) * 3;
    ld[ii][bt][0] = pp[0]; ld[ii][bt][1] = pp[1]; ld[ii][bt][2] = pp[2];
    *(float4*)&ld[ii][bt][4] = *(const float4*)(quat + ((size_t)bt * NN + i0 + ii) * 4);
  }
  __syncthreads();
  float acc[8] = {};
  for (int bt = 0; bt < BTT; ++bt) {
    const float* pj = pos + ((size_t)bt * NN + j) * 3;
    float pjx = pj[0], pjy = pj[1], pjz = pj[2];
    float4 qj = *(const float4*)(quat + ((size_t)bt * NN + j) * 4);
#pragma unroll
    for (int ii = 0; ii < 8; ++ii) {
      float4 pi = *(const float4*)&ld[ii][bt][0];
      float4 qi = *(const float4*)&ld[ii][bt][4];
      float dx = pi.x - pjx, dy = pi.y - pjy, dz = pi.z - pjz;
      float d2 = fmaf(dz, dz, fmaf(dy, dy, dx * dx));
      float dot = fmaf(qi.w, qj.w, fmaf(qi.z, qj.z, fmaf(qi.y, qj.y, qi.x * qj.x)));
      float tq = fmaf(-2.f, fabsf(dot), 2.f);
      acc[ii] += sqrtf(d2) + sqrtf(fmaxf(tq, 0.f));
    }
  }
  const int wv = tid >> 6;
#pragma unroll
  for (int ii = 0; ii < 8; ++ii) {
    float v = exp2f(-acc[ii] * KC);
    w[(size_t)(i0 + ii) * NN + j] = v;
    float s = v;
#pragma unroll
    for (int off = 1; off < 64; off <<= 1) s += __shfl_xor(s, off, 64);
    if ((tid & 63) == 0) wredS[wv][ii] = s;
  }
  __syncthreads();
  if (tid < 8)
    rsp[jx * 1024 + i0 + tid] = wredS[0][tid] + wredS[1][tid] + wredS[2][tid] + wredS[3][tid];
}

// ---------------------------------------------------------------------------
// blocks [0,256)   = trajB; blocks [256,512) = merged Q+K GEMM;
// blocks [512,768) = V GEMM. (R15 structure, validated: BK=64 + T2 swizzle.)
__global__ __launch_bounds__(256, 3) void qkv_trajB_kernel(const u16* __restrict__ Ab,
                                                        const u16* __restrict__ Wq,
                                                        const u16* __restrict__ Wk,
                                                        const u16* __restrict__ Wv,
                                                        const float* __restrict__ bq,
                                                        const float* __restrict__ bk,
                                                        const float* __restrict__ bv,
                                                        u16* __restrict__ Qb,
                                                        u16* __restrict__ Kb,
                                                        u16* __restrict__ VtT,
                                                        const float* __restrict__ wtr,
                                                        const float* __restrict__ rsp,
                                                        u16* __restrict__ tl) {
  const int tid = threadIdx.x;
  __shared__ __align__(16) u16 As[128 * 64];
  __shared__ __align__(16) u16 Bs[2][64 * 64];
  if (blockIdx.x < 256) {
    int base = blockIdx.x * 4;
#pragma unroll
    for (int r = 0; r < 4; ++r) {
      int i = base + r;
      float inv = TLC / (rsp[i] + rsp[1024 + i] + rsp[2048 + i] + rsp[3072 + i]);
      float4 w4 = *(const float4*)(wtr + (size_t)i * NN + tid * 4);
      ushort4 o = {f2bf(w4.x * inv), f2bf(w4.y * inv), f2bf(w4.z * inv), f2bf(w4.w * inv)};
      *(ushort4*)(tl + (size_t)i * NN + tid * 4) = o;
    }
    return;
  }
  const int bid = blockIdx.x - 256;
  const bool isQK = bid < 256;
  const int rem = bid & 255;
  const int bn = (rem & 15) << 6;          // 16 n-tiles of 64
  const int bm = (rem >> 4) << 7;          // 16 m-tiles of 128
  const int w = tid >> 6, l = tid & 63, g = l >> 4, ln = l & 15;
  const int lr = l >> 3;                   // row-in-chunk (= row&7 of staged row)
  const int sgc = ((l & 7) ^ lr) * 8;      // pre-swizzled global col slot (u16)
  const u16* ApA = Ab + (size_t)(bm + w * 32 + lr) * DD + sgc;
  u16* dAc = As + (w * 4) * 512;
  const int mw = (w & 1) * 64, nw = (w >> 1) * 32;
  const int lx = ln & 7;                   // row&7 for fragment reads
  f32x4 zero4 = {0.f, 0.f, 0.f, 0.f};
  if (isQK) {
    const u16* BqP = Wq + (size_t)(bn + w * 16 + lr) * DD + sgc;
    const u16* BkP = Wk + (size_t)(bn + w * 16 + lr) * DD + sgc;
    u16* dBq = Bs[0] + (w * 2) * 512;
    u16* dBk = Bs[1] + (w * 2) * 512;
    f32x4 acc[2][4][2];
#pragma unroll
    for (int z = 0; z < 2; ++z)
#pragma unroll
      for (int mt = 0; mt < 4; ++mt)
#pragma unroll
        for (int nt = 0; nt < 2; ++nt) acc[z][mt][nt] = zero4;
    for (int k0 = 0; k0 < DD; k0 += 64) {
      __syncthreads();
#pragma unroll
      for (int d = 0; d < 4; ++d)
        dma16(ApA + (size_t)(d * 8) * DD + k0, dAc + d * 512);
#pragma unroll
      for (int d = 0; d < 2; ++d) {
        dma16(BqP + (size_t)(d * 8) * DD + k0, dBq + d * 512);
        dma16(BkP + (size_t)(d * 8) * DD + k0, dBk + d * 512);
      }
      __syncthreads();
#pragma unroll
      for (int kc = 0; kc < 2; ++kc) {
        const int so = ((kc * 4 + g) ^ lx) * 8;
        bf16x8 afr[4], bqf[2], bkf[2];
#pragma unroll
        for (int nt = 0; nt < 2; ++nt) {
          int off = (nw + nt * 16 + ln) * 64 + so;
          bqf[nt] = *(const bf16x8*)&Bs[0][off];
          bkf[nt] = *(const bf16x8*)&Bs[1][off];
        }
#pragma unroll
        for (int mt = 0; mt < 4; ++mt)
          afr[mt] = *(const bf16x8*)&As[(mw + mt * 16 + ln) * 64 + so];
#pragma unroll
        for (int mt = 0; mt < 4; ++mt)
#pragma unroll
          for (int nt = 0; nt < 2; ++nt) {
            acc[0][mt][nt] = __builtin_amdgcn_mfma_f32_16x16x32_bf16(afr[mt], bqf[nt], acc[0][mt][nt], 0, 0, 0);
            acc[1][mt][nt] = __builtin_amdgcn_mfma_f32_16x16x32_bf16(afr[mt], bkf[nt], acc[1][mt][nt], 0, 0, 0);
          }
      }
    }
#pragma unroll
    for (int z = 0; z < 2; ++z) {
      u16* outp = z == 0 ? Qb : Kb;
      const float* bias = z == 0 ? bq : bk;
#pragma unroll
      for (int nt = 0; nt < 2; ++nt) {
        int n = bn + nw + nt * 16 + ln;
        float bb = bias[n];
#pragma unroll
        for (int mt = 0; mt < 4; ++mt) {
#pragma unroll
          for (int r = 0; r < 4; ++r) {
            int m = bm + mw + mt * 16 + g * 4 + r;
            outp[(size_t)m * DD + n] = f2bf(acc[z][mt][nt][r] + bb);
          }
        }
      }
    }
    return;
  }
  // V path
  const u16* BvP = Wv + (size_t)(bn + w * 16 + lr) * DD + sgc;
  u16* dBv = Bs[0] + (w * 2) * 512;
  f32x4 acc[4][2];
#pragma unroll
  for (int mt = 0; mt < 4; ++mt)
#pragma unroll
    for (int nt = 0; nt < 2; ++nt) acc[mt][nt] = zero4;
  for (int k0 = 0; k0 < DD; k0 += 64) {
    __syncthreads();
#pragma unroll
    for (int d = 0; d < 4; ++d)
      dma16(ApA + (size_t)(d * 8) * DD + k0, dAc + d * 512);
#pragma unroll
    for (int d = 0; d < 2; ++d)
      dma16(BvP + (size_t)(d * 8) * DD + k0, dBv + d * 512);
    __syncthreads();
#pragma unroll
    for (int kc = 0; kc < 2; ++kc) {
      const int so = ((kc * 4 + g) ^ lx) * 8;
      bf16x8 bfr[2], afr[4];
#pragma unroll
      for (int nt = 0; nt < 2; ++nt)
        bfr[nt] = *(const bf16x8*)&Bs[0][(nw + nt * 16 + ln) * 64 + so];
#pragma unroll
      for (int mt = 0; mt < 4; ++mt)
        afr[mt] = *(const bf16x8*)&As[(mw + mt * 16 + ln) * 64 + so];
#pragma unroll
      for (int mt = 0; mt < 4; ++mt)
#pragma unroll
        for (int nt = 0; nt < 2; ++nt)
          acc[mt][nt] = __builtin_amdgcn_mfma_f32_16x16x32_bf16(afr[mt], bfr[nt], acc[mt][nt], 0, 0, 0);
    }
  }
#pragma unroll
  for (int nt = 0; nt < 2; ++nt) {
    int n = bn + nw + nt * 16 + ln;
    float bb = bv[n];
    int row = (((bm >> 10) << 4) + (n >> 6)) * 64 + (n & 63);
#pragma unroll
    for (int mt = 0; mt < 4; ++mt) {
      int tok = (bm & 1023) + mw + mt * 16 + g * 4;
      ushort4 pk = {f2bf(acc[mt][nt][0] + bb), f2bf(acc[mt][nt][1] + bb),
                    f2bf(acc[mt][nt][2] + bb), f2bf(acc[mt][nt][3] + bb)};
      *(ushort4*)(VtT + (size_t)row * NN + tok) = pk;
    }
  }
}

// ---------------------------------------------------------------------------
// MFMA flash attention + E materialization. R19: EXACT revert to the R17
// structure (best measured: 191.5 us; att < 41 us). R18's 256-j staging
// dropped residency 3 -> 2 blocks/CU (51 KB -> 76 KB LDS) and regressed;
// cross-block overlap (m114) at 3 blocks/CU is worth more than halved
// barrier count. XCD swizzle kept (R17 win).
__global__ __launch_bounds__(256) void att_kernel(const u16* __restrict__ Qb,
                                                  const u16* __restrict__ Kb,
                                                  const u16* __restrict__ VtT,
                                                  const u16* __restrict__ tl,
                                                  u16* __restrict__ AOb,
                                                  float* __restrict__ Lv,
                                                  u16* __restrict__ Eb) {
  const int tid = threadIdx.x;
  // XCD swizzle: 512 blocks, 512%8==0 -> clean bijection (m204).
  const int wk = (blockIdx.x & 7) * 64 + (blockIdx.x >> 3);
  const int bh = wk >> 4;           // 4 consecutive heads per XCD chunk
  const int b = bh >> 4, h = bh & 15;
  const int i0 = (wk & 15) << 6;
  const int w = tid >> 6, l = tid & 63, g = l >> 4, ln = l & 15;
  const int wi0 = w * 16;
  __shared__ __align__(16) u16 Qs[8 * CH];
  __shared__ __align__(16) u16 Ks[2][8 * CH];
  __shared__ __align__(16) u16 Vts[2][8 * CH];
  __shared__ __align__(16) u16 Pt[64 * 72];
  __shared__ float lsc[64];
  const int c0 = 2 * w, c1 = 2 * w + 1;
  const int rr = 8 * (l >> 3);
  const int dcol = (l & 7) * 8;
  dma16(Qb + ((size_t)(b * NN) + i0 + c0 + rr) * DD + h * HDD + dcol, Qs + c0 * CH);
  dma16(Qb + ((size_t)(b * NN) + i0 + c1 + rr) * DD + h * HDD + dcol, Qs + c1 * CH);
  const int ig = i0 + wi0 + ln;
  u16* Erow = Eb + ((size_t)bh * NN + ig) * NN;   // E row for this thread's i
  const int lnlo = (ln & 7) * CH;
  const int lnhi = (ln >> 3) * 64;
  f32x4 zero4 = {0.f, 0.f, 0.f, 0.f};
  f32x4 oacc[4];
#pragma unroll
  for (int nt = 0; nt < 4; ++nt) oacc[nt] = zero4;
  float lacc = 0.f;
  for (int j0 = 0; j0 < NN; j0 += 128) {
    __syncthreads();
#pragma unroll
    for (int u = 0; u < 2; ++u) {
      int jb = j0 + u * 64;
      dma16(Kb + ((size_t)(b * NN) + jb + c0 + rr) * DD + h * HDD + dcol, Ks[u] + c0 * CH);
      dma16(Kb + ((size_t)(b * NN) + jb + c1 + rr) * DD + h * HDD + dcol, Ks[u] + c1 * CH);
      dma16(VtT + ((size_t)(bh * 64) + c0 + rr) * NN + jb + dcol, Vts[u] + c0 * CH);
      dma16(VtT + ((size_t)(bh * 64) + c1 + rr) * NN + jb + dcol, Vts[u] + c1 * CH);
    }
    ushort4 tlv[2][4];
#pragma unroll
    for (int u = 0; u < 2; ++u)
#pragma unroll
      for (int jt = 0; jt < 4; ++jt)
        tlv[u][jt] = *(const ushort4*)(tl + (size_t)ig * NN + j0 + u * 64 + jt * 16 + g * 4);
    __syncthreads();
    bf16x8 qf[2];
    qf[0] = *(const bf16x8*)&Qs[lnlo + (2 * w) * 64 + lnhi + g * 8];
    qf[1] = *(const bf16x8*)&Qs[lnlo + (2 * w) * 64 + lnhi + 32 + g * 8];
#pragma unroll
    for (int u = 0; u < 2; ++u) {
      f32x4 sacc[4];
      __builtin_amdgcn_s_setprio(1);
#pragma unroll
      for (int jt = 0; jt < 4; ++jt) {
        sacc[jt] = zero4;
#pragma unroll
        for (int kc = 0; kc < 2; ++kc) {
          bf16x8 af = *(const bf16x8*)&Ks[u][lnlo + (2 * jt) * 64 + lnhi + kc * 32 + g * 8];
          sacc[jt] = __builtin_amdgcn_mfma_f32_16x16x32_bf16(af, qf[kc], sacc[jt], 0, 0, 0);
        }
      }
      __builtin_amdgcn_s_setprio(0);
#pragma unroll
      for (int jt = 0; jt < 4; ++jt) {
        float e0 = exp2f(sacc[jt][0] * C1 + b2f(tlv[u][jt].x));
        float e1 = exp2f(sacc[jt][1] * C1 + b2f(tlv[u][jt].y));
        float e2 = exp2f(sacc[jt][2] * C1 + b2f(tlv[u][jt].z));
        float e3 = exp2f(sacc[jt][3] * C1 + b2f(tlv[u][jt].w));
        lacc += (e0 + e1) + (e2 + e3);
        uint2 pk = {pkbf(e0, e1), pkbf(e2, e3)};
        *(uint2*)(Pt + (wi0 + ln) * 72 + jt * 16 + g * 4) = pk;
        *(uint2*)(Erow + j0 + u * 64 + jt * 16 + g * 4) = pk;   // materialize E
      }
      bf16x8 pf[2];
      pf[0] = *(const bf16x8*)&Pt[(wi0 + ln) * 72 + g * 8];
      pf[1] = *(const bf16x8*)&Pt[(wi0 + ln) * 72 + 32 + g * 8];
      __builtin_amdgcn_s_setprio(1);
#pragma unroll
      for (int nt = 0; nt < 4; ++nt) {
#pragma unroll
        for (int kc = 0; kc < 2; ++kc) {
          bf16x8 vf = *(const bf16x8*)&Vts[u][lnlo + (2 * nt) * 64 + lnhi + kc * 32 + g * 8];
          oacc[nt] = __builtin_amdgcn_mfma_f32_16x16x32_bf16(pf[kc], vf, oacc[nt], 0, 0, 0);
        }
      }
      __builtin_amdgcn_s_setprio(0);
    }
  }
  lacc += __shfl_xor(lacc, 16, 64);
  lacc += __shfl_xor(lacc, 32, 64);
  if (g == 0) {
    Lv[(size_t)bh * NN + i0 + wi0 + ln] = lacc;
    lsc[wi0 + ln] = 1.f / lacc;
  }
  __syncthreads();
#pragma unroll
  for (int nt = 0; nt < 4; ++nt) {
    int d = nt * 16 + ln;
#pragma unroll
    for (int r = 0; r < 4; ++r) {
      int i = wi0 + g * 4 + r;
      float v = oacc[nt][r] * lsc[i];
      AOb[((size_t)(b * NN) + i0 + i) * DD + h * HDD + d] = f2bf(v);
    }
  }
}

// ---------------------------------------------------------------------------
// Fused final stage: blocks [0,256) = output projection GEMM (BK=64 +
// swizzle, R15-validated); blocks [256,768) = streaming entropy + certainty.
__global__ __launch_bounds__(256) void gemmo_ent_kernel(const u16* __restrict__ Ab,
                                                        const u16* __restrict__ Wb,
                                                        const float* __restrict__ bias,
                                                        float* __restrict__ C,
                                                        const u16* __restrict__ Eb,
                                                        const float* __restrict__ Lv,
                                                        const float* __restrict__ cert,
                                                        float* __restrict__ outc) {
  const int tid = threadIdx.x;
  __shared__ __align__(16) u16 As[128 * 64];
  __shared__ __align__(16) u16 Bs[64 * 64];
  __shared__ float linvS[4][16];
  __shared__ float redS[4][4];   // [wave][row]
  if (blockIdx.x >= 256) {
    const int e = blockIdx.x - 256;       // [0,512)
    const int b = e >> 8;
    const int ib4 = (e & 255) << 2;       // 4 rows per block
    if (tid < 64) {
      int r = tid >> 4, h = tid & 15;
      linvS[r][h] = 1.f / Lv[((size_t)(b * 16 + h)) * NN + ib4 + r];
    }
    __syncthreads();
    const int jb = tid * 4;               // 256 threads cover 1024 j
    float A[4];
#pragma unroll
    for (int r = 0; r < 4; ++r) {
      float s0 = 0.f, s1 = 0.f, s2 = 0.f, s3 = 0.f;
#pragma unroll
      for (int h = 0; h < 16; ++h) {
        ushort4 v = *(const ushort4*)(Eb + (((size_t)(b * 16 + h)) * NN + ib4 + r) * NN + jb);
        float li = linvS[r][h];
        s0 = fmaf(b2f(v.x), li, s0); s1 = fmaf(b2f(v.y), li, s1);
        s2 = fmaf(b2f(v.z), li, s2); s3 = fmaf(b2f(v.w), li, s3);
      }
      float p0 = fmaxf(s0 * (1.f / NHH), 1e-10f);
      float p1 = fmaxf(s1 * (1.f / NHH), 1e-10f);
      float p2 = fmaxf(s2 * (1.f / NHH), 1e-10f);
      float p3 = fmaxf(s3 * (1.f / NHH), 1e-10f);
      A[r] = p0 * __log2f(p0) + p1 * __log2f(p1) + p2 * __log2f(p2) + p3 * __log2f(p3);
    }
#pragma unroll
    for (int r = 0; r < 4; ++r)
#pragma unroll
      for (int off = 1; off < 64; off <<= 1) A[r] += __shfl_xor(A[r], off, 64);
    const int wv = tid >> 6;
    if ((tid & 63) == 0) {
#pragma unroll
      for (int r = 0; r < 4; ++r) redS[wv][r] = A[r];
    }
    __syncthreads();
    if (tid < 4) {
      float H = -LN2 * (redS[0][tid] + redS[1][tid] + redS[2][tid] + redS[3][tid]);
      int idx = b * NN + ib4 + tid;
      float sg = 1.f / (1.f + expf(H - HMAXL));
      outc[idx] = fmaxf(cert[idx], sg);
    }
    return;
  }
  const int bn = (blockIdx.x & 15) << 6;   // 16 n-tiles of 64
  const int bm = (blockIdx.x >> 4) << 7;   // 16 m-tiles of 128
  const int w = tid >> 6, l = tid & 63, g = l >> 4, ln = l & 15;
  const int lr = l >> 3;
  const int sgc = ((l & 7) ^ lr) * 8;
  const u16* ApA = Ab + (size_t)(bm + w * 32 + lr) * DD + sgc;
  const u16* BoP = Wb + (size_t)(bn + w * 16 + lr) * DD + sgc;
  u16* dAc = As + (w * 4) * 512;
  u16* dBo = Bs + (w * 2) * 512;
  const int mw = (w & 1) * 64, nw = (w >> 1) * 32;
  const int lx = ln & 7;
  f32x4 zero4 = {0.f, 0.f, 0.f, 0.f};
  f32x4 acc[4][2];
#pragma unroll
  for (int mt = 0; mt < 4; ++mt)
#pragma unroll
    for (int nt = 0; nt < 2; ++nt) acc[mt][nt] = zero4;
  for (int k0 = 0; k0 < DD; k0 += 64) {
    __syncthreads();
#pragma unroll
    for (int d = 0; d < 4; ++d)
      dma16(ApA + (size_t)(d * 8) * DD + k0, dAc + d * 512);
#pragma unroll
    for (int d = 0; d < 2; ++d)
      dma16(BoP + (size_t)(d * 8) * DD + k0, dBo + d * 512);
    __syncthreads();
#pragma unroll
    for (int kc = 0; kc < 2; ++kc) {
      const int so = ((kc * 4 + g) ^ lx) * 8;
      bf16x8 bfr[2], afr[4];
#pragma unroll
      for (int nt = 0; nt < 2; ++nt)
        bfr[nt] = *(const bf16x8*)&Bs[(nw + nt * 16 + ln) * 64 + so];
#pragma unroll
      for (int mt = 0; mt < 4; ++mt)
        afr[mt] = *(const bf16x8*)&As[(mw + mt * 16 + ln) * 64 + so];
#pragma unroll
      for (int mt = 0; mt < 4; ++mt)
#pragma unroll
        for (int nt = 0; nt < 2; ++nt)
          acc[mt][nt] = __builtin_amdgcn_mfma_f32_16x16x32_bf16(afr[mt], bfr[nt], acc[mt][nt], 0, 0, 0);
    }
  }
#pragma unroll
  for (int nt = 0; nt < 2; ++nt) {
    int n = bn + nw + nt * 16 + ln;
    float bb = bias[n];
#pragma unroll
    for (int mt = 0; mt < 4; ++mt) {
#pragma unroll
      for (int r = 0; r < 4; ++r) {
        int m = bm + mw + mt * 16 + g * 4 + r;
        C[(size_t)m * DD + n] = acc[mt][nt][r] + bb;
      }
    }
  }
}

// ---------------------------------------------------------------------------
extern "C" void kernel_launch(void* const* d_in, const int* in_sizes, int n_in,
                              void* d_out, int out_size, void* d_ws, size_t ws_size,
                              hipStream_t stream) {
  const float* data      = (const float*)d_in[0];
  const float* traj_pos  = (const float*)d_in[1];
  const float* traj_quat = (const float*)d_in[2];
  const float* certainty = (const float*)d_in[3];
  const float* Wq = (const float*)d_in[4];
  const float* bq = (const float*)d_in[5];
  const float* Wk = (const float*)d_in[6];
  const float* bk = (const float*)d_in[7];
  const float* Wv = (const float*)d_in[8];
  const float* bv = (const float*)d_in[9];
  const float* Wo = (const float*)d_in[10];
  const float* bo = (const float*)d_in[11];

  float* ws = (float*)d_ws;
  float* wtr  = ws + TRAJ_OFF;
  u16* tl    = (u16*)(ws + TL_OFF);
  u16* datab = (u16*)(ws + DATAB_OFF);
  u16* wqb   = (u16*)(ws + WQB_OFF);
  u16* wkb   = (u16*)(ws + WKB_OFF);
  u16* wvb   = (u16*)(ws + WVB_OFF);
  u16* wob   = (u16*)(ws + WOB_OFF);
  u16* Qb    = (u16*)(ws + QB_OFF);
  u16* Kb    = (u16*)(ws + KB_OFF);
  u16* VtT   = (u16*)(ws + VT_OFF);
  u16* AOb   = (u16*)(ws + AOB_OFF);
  float* Lv   = ws + LV_OFF;
  float* rsp  = ws + RSP_OFF;
  u16* Eb    = (u16*)(ws + EB_OFF);
  float* out  = (float*)d_out;
  float* outc = out + (size_t)NB * NN * DD;

  prep_kernel<<<6656, 256, 0, stream>>>(data, Wq, Wk, Wv, Wo,
                                        datab, wqb, wkb, wvb, wob,
                                        traj_pos, traj_quat, wtr, rsp);
  qkv_trajB_kernel<<<768, 256, 0, stream>>>(datab, wqb, wkb, wvb, bq, bk, bv,
                                            Qb, Kb, VtT, wtr, rsp, tl);
  att_kernel<<<512, 256, 0, stream>>>(Qb, Kb, VtT, tl, AOb, Lv, Eb);
  gemmo_ent_kernel<<<768, 256, 0, stream>>>(AOb, wob, bo, out, Eb, Lv, certainty, outc);
}

// Round 12
// 187.910 us; speedup vs baseline: 1.0402x; 1.0326x over previous
//
#include <hip/hip_runtime.h>
#include <math.h>

#define NB 2
#define NN 1024
#define DD 1024
#define NHH 16
#define HDD 64
#define BTT 20
#define IB 2      // trajA i-rows per block (R20: was 8 -> 2048 blocks, 8/CU)

typedef unsigned short u16;
typedef short bf16x8 __attribute__((ext_vector_type(8)));
typedef float f32x4 __attribute__((ext_vector_type(4)));

#define HMAXL 6.93147180559945f
#define LN2 0.69314718055994531f
#define C1 0.18033688011112042f   // 0.125 * log2(e)
#define TLC 0.72134752044448170f  // 0.5 * log2(e)
#define KC  0.072134752044448170f // log2(e) / 20
#define CH 520                    // padded chunk stride (1024B chunk + 16B pad) in u16

// ws offsets in floats (workspace is 256 MiB per the re-poison fill WRITE_SIZE)
#define TRAJ_OFF 0          // unnormalized w, fp32 N*N
#define TL_OFF    1048576
#define DATAB_OFF 1572864
#define WQB_OFF   2621440
#define WKB_OFF   3145728
#define WVB_OFF   3670016
#define WOB_OFF   4194304
#define QB_OFF    4718592
#define KB_OFF    5767168
#define VT_OFF    6815744
#define AOB_OFF   7864320
#define LV_OFF    8912896   // 32768 f
#define RSP_OFF   8978432   // 4*1024 f
#define EB_OFF    8982528   // E matrix, bf16 (b,h,i,j) = 32M u16 = 16M floats

__device__ __forceinline__ float b2f(u16 h) { return __uint_as_float(((unsigned)h) << 16); }
__device__ __forceinline__ u16 f2bf(float f) {
  unsigned u = __float_as_uint(f);
  return (u16)((u + 0x7fffu + ((u >> 16) & 1u)) >> 16);
}
// HW packed f32->bf16 RTNE convert (gfx950 v_cvt_pk_bf16_f32).
__device__ __forceinline__ unsigned pkbf(float a, float b) {
  unsigned r;
  asm("v_cvt_pk_bf16_f32 %0, %1, %2" : "=v"(r) : "v"(a), "v"(b));
  return r;
}
__device__ __forceinline__ void dma16(const void* g, void* l) {
  __builtin_amdgcn_global_load_lds((const __attribute__((address_space(1))) void*)g,
                                   (__attribute__((address_space(3))) void*)l, 16, 0, 0);
}

// ---------------------------------------------------------------------------
// Merged prep: blocks [0,2048) = trajA (R20: latency-bound at 2 blocks/CU --
// VALUBusy 52%, Occ 28%, ideal-VALU floor ~12us vs 45 measured. Split i-group
// 8 -> IB=2 rows/block => 2048 blocks = 8/CU, 4x the TLP to hide the ~200cyc
// L2 pos/quat loads. Same per-(i,j) arithmetic + loop order -> bit-identical);
// blocks [2048,8192) = fp32->bf16 conversion (HBM-bound, backfills).
__global__ __launch_bounds__(256) void prep_kernel(const float* __restrict__ data,
                                                   const float* __restrict__ w0,
                                                   const float* __restrict__ w1,
                                                   const float* __restrict__ w2,
                                                   const float* __restrict__ w3,
                                                   u16* __restrict__ dd,
                                                   u16* __restrict__ d0, u16* __restrict__ d1,
                                                   u16* __restrict__ d2, u16* __restrict__ d3,
                                                   const float* __restrict__ pos,
                                                   const float* __restrict__ quat,
                                                   float* __restrict__ w,
                                                   float* __restrict__ rsp) {
  const int tid = threadIdx.x;
  const int bid = blockIdx.x;
  __shared__ float ld[IB][BTT][8];
  __shared__ float wredS[4][IB];
  if (bid >= 2048) {
    // conversion part
    int cb = bid - 2048;
    int z = cb >> 10;
    const float* s;
    u16* d;
    size_t off = 0;
    if (z < 2) { s = data; d = dd; off = (size_t)z * 1048576; }
    else if (z == 2) { s = w0; d = d0; }
    else if (z == 3) { s = w1; d = d1; }
    else if (z == 4) { s = w2; d = d2; }
    else { s = w3; d = d3; }
    size_t i = off + (size_t)((cb & 1023) * 256 + tid) * 4;
    float4 v = *(const float4*)(s + i);
    ushort4 o = {f2bf(v.x), f2bf(v.y), f2bf(v.z), f2bf(v.w)};
    *(ushort4*)(d + i) = o;
    return;
  }
  // trajA part
  const int jx = bid & 3;
  const int j = jx * 256 + tid;
  const int i0 = (bid >> 2) * IB;
  if (tid < IB * BTT) {
    int ii = tid / BTT, bt = tid % BTT;
    const float* pp = pos + ((size_t)bt * NN + i0 + ii) * 3;
    ld[ii][bt][0] = pp[0]; ld[ii][bt][1] = pp[1]; ld[ii][bt][2] = pp[2];
    *(float4*)&ld[ii][bt][4] = *(const float4*)(quat + ((size_t)bt * NN + i0 + ii) * 4);
  }
  __syncthreads();
  float acc[IB] = {};
  for (int bt = 0; bt < BTT; ++bt) {
    const float* pj = pos + ((size_t)bt * NN + j) * 3;
    float pjx = pj[0], pjy = pj[1], pjz = pj[2];
    float4 qj = *(const float4*)(quat + ((size_t)bt * NN + j) * 4);
#pragma unroll
    for (int ii = 0; ii < IB; ++ii) {
      float4 pi = *(const float4*)&ld[ii][bt][0];
      float4 qi = *(const float4*)&ld[ii][bt][4];
      float dx = pi.x - pjx, dy = pi.y - pjy, dz = pi.z - pjz;
      float d2 = fmaf(dz, dz, fmaf(dy, dy, dx * dx));
      float dot = fmaf(qi.w, qj.w, fmaf(qi.z, qj.z, fmaf(qi.y, qj.y, qi.x * qj.x)));
      float tq = fmaf(-2.f, fabsf(dot), 2.f);
      acc[ii] += sqrtf(d2) + sqrtf(fmaxf(tq, 0.f));
    }
  }
  const int wv = tid >> 6;
#pragma unroll
  for (int ii = 0; ii < IB; ++ii) {
    float v = exp2f(-acc[ii] * KC);
    w[(size_t)(i0 + ii) * NN + j] = v;
    float s = v;
#pragma unroll
    for (int off = 1; off < 64; off <<= 1) s += __shfl_xor(s, off, 64);
    if ((tid & 63) == 0) wredS[wv][ii] = s;
  }
  __syncthreads();
  if (tid < IB)
    rsp[jx * 1024 + i0 + tid] = wredS[0][tid] + wredS[1][tid] + wredS[2][tid] + wredS[3][tid];
}

// ---------------------------------------------------------------------------
// blocks [0,256)   = trajB; blocks [256,512) = merged Q+K GEMM;
// blocks [512,768) = V GEMM. (R15 structure, validated: BK=64 + T2 swizzle.)
__global__ __launch_bounds__(256, 3) void qkv_trajB_kernel(const u16* __restrict__ Ab,
                                                        const u16* __restrict__ Wq,
                                                        const u16* __restrict__ Wk,
                                                        const u16* __restrict__ Wv,
                                                        const float* __restrict__ bq,
                                                        const float* __restrict__ bk,
                                                        const float* __restrict__ bv,
                                                        u16* __restrict__ Qb,
                                                        u16* __restrict__ Kb,
                                                        u16* __restrict__ VtT,
                                                        const float* __restrict__ wtr,
                                                        const float* __restrict__ rsp,
                                                        u16* __restrict__ tl) {
  const int tid = threadIdx.x;
  __shared__ __align__(16) u16 As[128 * 64];
  __shared__ __align__(16) u16 Bs[2][64 * 64];
  if (blockIdx.x < 256) {
    int base = blockIdx.x * 4;
#pragma unroll
    for (int r = 0; r < 4; ++r) {
      int i = base + r;
      float inv = TLC / (rsp[i] + rsp[1024 + i] + rsp[2048 + i] + rsp[3072 + i]);
      float4 w4 = *(const float4*)(wtr + (size_t)i * NN + tid * 4);
      ushort4 o = {f2bf(w4.x * inv), f2bf(w4.y * inv), f2bf(w4.z * inv), f2bf(w4.w * inv)};
      *(ushort4*)(tl + (size_t)i * NN + tid * 4) = o;
    }
    return;
  }
  const int bid = blockIdx.x - 256;
  const bool isQK = bid < 256;
  const int rem = bid & 255;
  const int bn = (rem & 15) << 6;          // 16 n-tiles of 64
  const int bm = (rem >> 4) << 7;          // 16 m-tiles of 128
  const int w = tid >> 6, l = tid & 63, g = l >> 4, ln = l & 15;
  const int lr = l >> 3;                   // row-in-chunk (= row&7 of staged row)
  const int sgc = ((l & 7) ^ lr) * 8;      // pre-swizzled global col slot (u16)
  const u16* ApA = Ab + (size_t)(bm + w * 32 + lr) * DD + sgc;
  u16* dAc = As + (w * 4) * 512;
  const int mw = (w & 1) * 64, nw = (w >> 1) * 32;
  const int lx = ln & 7;                   // row&7 for fragment reads
  f32x4 zero4 = {0.f, 0.f, 0.f, 0.f};
  if (isQK) {
    const u16* BqP = Wq + (size_t)(bn + w * 16 + lr) * DD + sgc;
    const u16* BkP = Wk + (size_t)(bn + w * 16 + lr) * DD + sgc;
    u16* dBq = Bs[0] + (w * 2) * 512;
    u16* dBk = Bs[1] + (w * 2) * 512;
    f32x4 acc[2][4][2];
#pragma unroll
    for (int z = 0; z < 2; ++z)
#pragma unroll
      for (int mt = 0; mt < 4; ++mt)
#pragma unroll
        for (int nt = 0; nt < 2; ++nt) acc[z][mt][nt] = zero4;
    for (int k0 = 0; k0 < DD; k0 += 64) {
      __syncthreads();
#pragma unroll
      for (int d = 0; d < 4; ++d)
        dma16(ApA + (size_t)(d * 8) * DD + k0, dAc + d * 512);
#pragma unroll
      for (int d = 0; d < 2; ++d) {
        dma16(BqP + (size_t)(d * 8) * DD + k0, dBq + d * 512);
        dma16(BkP + (size_t)(d * 8) * DD + k0, dBk + d * 512);
      }
      __syncthreads();
#pragma unroll
      for (int kc = 0; kc < 2; ++kc) {
        const int so = ((kc * 4 + g) ^ lx) * 8;
        bf16x8 afr[4], bqf[2], bkf[2];
#pragma unroll
        for (int nt = 0; nt < 2; ++nt) {
          int off = (nw + nt * 16 + ln) * 64 + so;
          bqf[nt] = *(const bf16x8*)&Bs[0][off];
          bkf[nt] = *(const bf16x8*)&Bs[1][off];
        }
#pragma unroll
        for (int mt = 0; mt < 4; ++mt)
          afr[mt] = *(const bf16x8*)&As[(mw + mt * 16 + ln) * 64 + so];
#pragma unroll
        for (int mt = 0; mt < 4; ++mt)
#pragma unroll
          for (int nt = 0; nt < 2; ++nt) {
            acc[0][mt][nt] = __builtin_amdgcn_mfma_f32_16x16x32_bf16(afr[mt], bqf[nt], acc[0][mt][nt], 0, 0, 0);
            acc[1][mt][nt] = __builtin_amdgcn_mfma_f32_16x16x32_bf16(afr[mt], bkf[nt], acc[1][mt][nt], 0, 0, 0);
          }
      }
    }
#pragma unroll
    for (int z = 0; z < 2; ++z) {
      u16* outp = z == 0 ? Qb : Kb;
      const float* bias = z == 0 ? bq : bk;
#pragma unroll
      for (int nt = 0; nt < 2; ++nt) {
        int n = bn + nw + nt * 16 + ln;
        float bb = bias[n];
#pragma unroll
        for (int mt = 0; mt < 4; ++mt) {
#pragma unroll
          for (int r = 0; r < 4; ++r) {
            int m = bm + mw + mt * 16 + g * 4 + r;
            outp[(size_t)m * DD + n] = f2bf(acc[z][mt][nt][r] + bb);
          }
        }
      }
    }
    return;
  }
  // V path
  const u16* BvP = Wv + (size_t)(bn + w * 16 + lr) * DD + sgc;
  u16* dBv = Bs[0] + (w * 2) * 512;
  f32x4 acc[4][2];
#pragma unroll
  for (int mt = 0; mt < 4; ++mt)
#pragma unroll
    for (int nt = 0; nt < 2; ++nt) acc[mt][nt] = zero4;
  for (int k0 = 0; k0 < DD; k0 += 64) {
    __syncthreads();
#pragma unroll
    for (int d = 0; d < 4; ++d)
      dma16(ApA + (size_t)(d * 8) * DD + k0, dAc + d * 512);
#pragma unroll
    for (int d = 0; d < 2; ++d)
      dma16(BvP + (size_t)(d * 8) * DD + k0, dBv + d * 512);
    __syncthreads();
#pragma unroll
    for (int kc = 0; kc < 2; ++kc) {
      const int so = ((kc * 4 + g) ^ lx) * 8;
      bf16x8 bfr[2], afr[4];
#pragma unroll
      for (int nt = 0; nt < 2; ++nt)
        bfr[nt] = *(const bf16x8*)&Bs[0][(nw + nt * 16 + ln) * 64 + so];
#pragma unroll
      for (int mt = 0; mt < 4; ++mt)
        afr[mt] = *(const bf16x8*)&As[(mw + mt * 16 + ln) * 64 + so];
#pragma unroll
      for (int mt = 0; mt < 4; ++mt)
#pragma unroll
        for (int nt = 0; nt < 2; ++nt)
          acc[mt][nt] = __builtin_amdgcn_mfma_f32_16x16x32_bf16(afr[mt], bfr[nt], acc[mt][nt], 0, 0, 0);
    }
  }
#pragma unroll
  for (int nt = 0; nt < 2; ++nt) {
    int n = bn + nw + nt * 16 + ln;
    float bb = bv[n];
    int row = (((bm >> 10) << 4) + (n >> 6)) * 64 + (n & 63);
#pragma unroll
    for (int mt = 0; mt < 4; ++mt) {
      int tok = (bm & 1023) + mw + mt * 16 + g * 4;
      ushort4 pk = {f2bf(acc[mt][nt][0] + bb), f2bf(acc[mt][nt][1] + bb),
                    f2bf(acc[mt][nt][2] + bb), f2bf(acc[mt][nt][3] + bb)};
      *(ushort4*)(VtT + (size_t)row * NN + tok) = pk;
    }
  }
}

// ---------------------------------------------------------------------------
// MFMA flash attention + E materialization (R17/R19 structure: staged K/V,
// 51 KB LDS -> 3 blocks/CU, XCD swizzle). Unchanged.
__global__ __launch_bounds__(256) void att_kernel(const u16* __restrict__ Qb,
                                                  const u16* __restrict__ Kb,
                                                  const u16* __restrict__ VtT,
                                                  const u16* __restrict__ tl,
                                                  u16* __restrict__ AOb,
                                                  float* __restrict__ Lv,
                                                  u16* __restrict__ Eb) {
  const int tid = threadIdx.x;
  // XCD swizzle: 512 blocks, 512%8==0 -> clean bijection (m204).
  const int wk = (blockIdx.x & 7) * 64 + (blockIdx.x >> 3);
  const int bh = wk >> 4;           // 4 consecutive heads per XCD chunk
  const int b = bh >> 4, h = bh & 15;
  const int i0 = (wk & 15) << 6;
  const int w = tid >> 6, l = tid & 63, g = l >> 4, ln = l & 15;
  const int wi0 = w * 16;
  __shared__ __align__(16) u16 Qs[8 * CH];
  __shared__ __align__(16) u16 Ks[2][8 * CH];
  __shared__ __align__(16) u16 Vts[2][8 * CH];
  __shared__ __align__(16) u16 Pt[64 * 72];
  __shared__ float lsc[64];
  const int c0 = 2 * w, c1 = 2 * w + 1;
  const int rr = 8 * (l >> 3);
  const int dcol = (l & 7) * 8;
  dma16(Qb + ((size_t)(b * NN) + i0 + c0 + rr) * DD + h * HDD + dcol, Qs + c0 * CH);
  dma16(Qb + ((size_t)(b * NN) + i0 + c1 + rr) * DD + h * HDD + dcol, Qs + c1 * CH);
  const int ig = i0 + wi0 + ln;
  u16* Erow = Eb + ((size_t)bh * NN + ig) * NN;   // E row for this thread's i
  const int lnlo = (ln & 7) * CH;
  const int lnhi = (ln >> 3) * 64;
  f32x4 zero4 = {0.f, 0.f, 0.f, 0.f};
  f32x4 oacc[4];
#pragma unroll
  for (int nt = 0; nt < 4; ++nt) oacc[nt] = zero4;
  float lacc = 0.f;
  for (int j0 = 0; j0 < NN; j0 += 128) {
    __syncthreads();
#pragma unroll
    for (int u = 0; u < 2; ++u) {
      int jb = j0 + u * 64;
      dma16(Kb + ((size_t)(b * NN) + jb + c0 + rr) * DD + h * HDD + dcol, Ks[u] + c0 * CH);
      dma16(Kb + ((size_t)(b * NN) + jb + c1 + rr) * DD + h * HDD + dcol, Ks[u] + c1 * CH);
      dma16(VtT + ((size_t)(bh * 64) + c0 + rr) * NN + jb + dcol, Vts[u] + c0 * CH);
      dma16(VtT + ((size_t)(bh * 64) + c1 + rr) * NN + jb + dcol, Vts[u] + c1 * CH);
    }
    ushort4 tlv[2][4];
#pragma unroll
    for (int u = 0; u < 2; ++u)
#pragma unroll
      for (int jt = 0; jt < 4; ++jt)
        tlv[u][jt] = *(const ushort4*)(tl + (size_t)ig * NN + j0 + u * 64 + jt * 16 + g * 4);
    __syncthreads();
    bf16x8 qf[2];
    qf[0] = *(const bf16x8*)&Qs[lnlo + (2 * w) * 64 + lnhi + g * 8];
    qf[1] = *(const bf16x8*)&Qs[lnlo + (2 * w) * 64 + lnhi + 32 + g * 8];
#pragma unroll
    for (int u = 0; u < 2; ++u) {
      f32x4 sacc[4];
      __builtin_amdgcn_s_setprio(1);
#pragma unroll
      for (int jt = 0; jt < 4; ++jt) {
        sacc[jt] = zero4;
#pragma unroll
        for (int kc = 0; kc < 2; ++kc) {
          bf16x8 af = *(const bf16x8*)&Ks[u][lnlo + (2 * jt) * 64 + lnhi + kc * 32 + g * 8];
          sacc[jt] = __builtin_amdgcn_mfma_f32_16x16x32_bf16(af, qf[kc], sacc[jt], 0, 0, 0);
        }
      }
      __builtin_amdgcn_s_setprio(0);
#pragma unroll
      for (int jt = 0; jt < 4; ++jt) {
        float e0 = exp2f(sacc[jt][0] * C1 + b2f(tlv[u][jt].x));
        float e1 = exp2f(sacc[jt][1] * C1 + b2f(tlv[u][jt].y));
        float e2 = exp2f(sacc[jt][2] * C1 + b2f(tlv[u][jt].z));
        float e3 = exp2f(sacc[jt][3] * C1 + b2f(tlv[u][jt].w));
        lacc += (e0 + e1) + (e2 + e3);
        uint2 pk = {pkbf(e0, e1), pkbf(e2, e3)};
        *(uint2*)(Pt + (wi0 + ln) * 72 + jt * 16 + g * 4) = pk;
        *(uint2*)(Erow + j0 + u * 64 + jt * 16 + g * 4) = pk;   // materialize E
      }
      bf16x8 pf[2];
      pf[0] = *(const bf16x8*)&Pt[(wi0 + ln) * 72 + g * 8];
      pf[1] = *(const bf16x8*)&Pt[(wi0 + ln) * 72 + 32 + g * 8];
      __builtin_amdgcn_s_setprio(1);
#pragma unroll
      for (int nt = 0; nt < 4; ++nt) {
#pragma unroll
        for (int kc = 0; kc < 2; ++kc) {
          bf16x8 vf = *(const bf16x8*)&Vts[u][lnlo + (2 * nt) * 64 + lnhi + kc * 32 + g * 8];
          oacc[nt] = __builtin_amdgcn_mfma_f32_16x16x32_bf16(pf[kc], vf, oacc[nt], 0, 0, 0);
        }
      }
      __builtin_amdgcn_s_setprio(0);
    }
  }
  lacc += __shfl_xor(lacc, 16, 64);
  lacc += __shfl_xor(lacc, 32, 64);
  if (g == 0) {
    Lv[(size_t)bh * NN + i0 + wi0 + ln] = lacc;
    lsc[wi0 + ln] = 1.f / lacc;
  }
  __syncthreads();
#pragma unroll
  for (int nt = 0; nt < 4; ++nt) {
    int d = nt * 16 + ln;
#pragma unroll
    for (int r = 0; r < 4; ++r) {
      int i = wi0 + g * 4 + r;
      float v = oacc[nt][r] * lsc[i];
      AOb[((size_t)(b * NN) + i0 + i) * DD + h * HDD + d] = f2bf(v);
    }
  }
}

// ---------------------------------------------------------------------------
// Fused final stage: blocks [0,256) = output projection GEMM (BK=64 +
// swizzle, R15-validated); blocks [256,768) = streaming entropy + certainty.
__global__ __launch_bounds__(256) void gemmo_ent_kernel(const u16* __restrict__ Ab,
                                                        const u16* __restrict__ Wb,
                                                        const float* __restrict__ bias,
                                                        float* __restrict__ C,
                                                        const u16* __restrict__ Eb,
                                                        const float* __restrict__ Lv,
                                                        const float* __restrict__ cert,
                                                        float* __restrict__ outc) {
  const int tid = threadIdx.x;
  __shared__ __align__(16) u16 As[128 * 64];
  __shared__ __align__(16) u16 Bs[64 * 64];
  __shared__ float linvS[4][16];
  __shared__ float redS[4][4];   // [wave][row]
  if (blockIdx.x >= 256) {
    const int e = blockIdx.x - 256;       // [0,512)
    const int b = e >> 8;
    const int ib4 = (e & 255) << 2;       // 4 rows per block
    if (tid < 64) {
      int r = tid >> 4, h = tid & 15;
      linvS[r][h] = 1.f / Lv[((size_t)(b * 16 + h)) * NN + ib4 + r];
    }
    __syncthreads();
    const int jb = tid * 4;               // 256 threads cover 1024 j
    float A[4];
#pragma unroll
    for (int r = 0; r < 4; ++r) {
      float s0 = 0.f, s1 = 0.f, s2 = 0.f, s3 = 0.f;
#pragma unroll
      for (int h = 0; h < 16; ++h) {
        ushort4 v = *(const ushort4*)(Eb + (((size_t)(b * 16 + h)) * NN + ib4 + r) * NN + jb);
        float li = linvS[r][h];
        s0 = fmaf(b2f(v.x), li, s0); s1 = fmaf(b2f(v.y), li, s1);
        s2 = fmaf(b2f(v.z), li, s2); s3 = fmaf(b2f(v.w), li, s3);
      }
      float p0 = fmaxf(s0 * (1.f / NHH), 1e-10f);
      float p1 = fmaxf(s1 * (1.f / NHH), 1e-10f);
      float p2 = fmaxf(s2 * (1.f / NHH), 1e-10f);
      float p3 = fmaxf(s3 * (1.f / NHH), 1e-10f);
      A[r] = p0 * __log2f(p0) + p1 * __log2f(p1) + p2 * __log2f(p2) + p3 * __log2f(p3);
    }
#pragma unroll
    for (int r = 0; r < 4; ++r)
#pragma unroll
      for (int off = 1; off < 64; off <<= 1) A[r] += __shfl_xor(A[r], off, 64);
    const int wv = tid >> 6;
    if ((tid & 63) == 0) {
#pragma unroll
      for (int r = 0; r < 4; ++r) redS[wv][r] = A[r];
    }
    __syncthreads();
    if (tid < 4) {
      float H = -LN2 * (redS[0][tid] + redS[1][tid] + redS[2][tid] + redS[3][tid]);
      int idx = b * NN + ib4 + tid;
      float sg = 1.f / (1.f + expf(H - HMAXL));
      outc[idx] = fmaxf(cert[idx], sg);
    }
    return;
  }
  const int bn = (blockIdx.x & 15) << 6;   // 16 n-tiles of 64
  const int bm = (blockIdx.x >> 4) << 7;   // 16 m-tiles of 128
  const int w = tid >> 6, l = tid & 63, g = l >> 4, ln = l & 15;
  const int lr = l >> 3;
  const int sgc = ((l & 7) ^ lr) * 8;
  const u16* ApA = Ab + (size_t)(bm + w * 32 + lr) * DD + sgc;
  const u16* BoP = Wb + (size_t)(bn + w * 16 + lr) * DD + sgc;
  u16* dAc = As + (w * 4) * 512;
  u16* dBo = Bs + (w * 2) * 512;
  const int mw = (w & 1) * 64, nw = (w >> 1) * 32;
  const int lx = ln & 7;
  f32x4 zero4 = {0.f, 0.f, 0.f, 0.f};
  f32x4 acc[4][2];
#pragma unroll
  for (int mt = 0; mt < 4; ++mt)
#pragma unroll
    for (int nt = 0; nt < 2; ++nt) acc[mt][nt] = zero4;
  for (int k0 = 0; k0 < DD; k0 += 64) {
    __syncthreads();
#pragma unroll
    for (int d = 0; d < 4; ++d)
      dma16(ApA + (size_t)(d * 8) * DD + k0, dAc + d * 512);
#pragma unroll
    for (int d = 0; d < 2; ++d)
      dma16(BoP + (size_t)(d * 8) * DD + k0, dBo + d * 512);
    __syncthreads();
#pragma unroll
    for (int kc = 0; kc < 2; ++kc) {
      const int so = ((kc * 4 + g) ^ lx) * 8;
      bf16x8 bfr[2], afr[4];
#pragma unroll
      for (int nt = 0; nt < 2; ++nt)
        bfr[nt] = *(const bf16x8*)&Bs[(nw + nt * 16 + ln) * 64 + so];
#pragma unroll
      for (int mt = 0; mt < 4; ++mt)
        afr[mt] = *(const bf16x8*)&As[(mw + mt * 16 + ln) * 64 + so];
#pragma unroll
      for (int mt = 0; mt < 4; ++mt)
#pragma unroll
        for (int nt = 0; nt < 2; ++nt)
          acc[mt][nt] = __builtin_amdgcn_mfma_f32_16x16x32_bf16(afr[mt], bfr[nt], acc[mt][nt], 0, 0, 0);
    }
  }
#pragma unroll
  for (int nt = 0; nt < 2; ++nt) {
    int n = bn + nw + nt * 16 + ln;
    float bb = bias[n];
#pragma unroll
    for (int mt = 0; mt < 4; ++mt) {
#pragma unroll
      for (int r = 0; r < 4; ++r) {
        int m = bm + mw + mt * 16 + g * 4 + r;
        C[(size_t)m * DD + n] = acc[mt][nt][r] + bb;
      }
    }
  }
}

// ---------------------------------------------------------------------------
extern "C" void kernel_launch(void* const* d_in, const int* in_sizes, int n_in,
                              void* d_out, int out_size, void* d_ws, size_t ws_size,
                              hipStream_t stream) {
  const float* data      = (const float*)d_in[0];
  const float* traj_pos  = (const float*)d_in[1];
  const float* traj_quat = (const float*)d_in[2];
  const float* certainty = (const float*)d_in[3];
  const float* Wq = (const float*)d_in[4];
  const float* bq = (const float*)d_in[5];
  const float* Wk = (const float*)d_in[6];
  const float* bk = (const float*)d_in[7];
  const float* Wv = (const float*)d_in[8];
  const float* bv = (const float*)d_in[9];
  const float* Wo = (const float*)d_in[10];
  const float* bo = (const float*)d_in[11];

  float* ws = (float*)d_ws;
  float* wtr  = ws + TRAJ_OFF;
  u16* tl    = (u16*)(ws + TL_OFF);
  u16* datab = (u16*)(ws + DATAB_OFF);
  u16* wqb   = (u16*)(ws + WQB_OFF);
  u16* wkb   = (u16*)(ws + WKB_OFF);
  u16* wvb   = (u16*)(ws + WVB_OFF);
  u16* wob   = (u16*)(ws + WOB_OFF);
  u16* Qb    = (u16*)(ws + QB_OFF);
  u16* Kb    = (u16*)(ws + KB_OFF);
  u16* VtT   = (u16*)(ws + VT_OFF);
  u16* AOb   = (u16*)(ws + AOB_OFF);
  float* Lv   = ws + LV_OFF;
  float* rsp  = ws + RSP_OFF;
  u16* Eb    = (u16*)(ws + EB_OFF);
  float* out  = (float*)d_out;
  float* outc = out + (size_t)NB * NN * DD;

  prep_kernel<<<8192, 256, 0, stream>>>(data, Wq, Wk, Wv, Wo,
                                        datab, wqb, wkb, wvb, wob,
                                        traj_pos, traj_quat, wtr, rsp);
  qkv_trajB_kernel<<<768, 256, 0, stream>>>(datab, wqb, wkb, wvb, bq, bk, bv,
                                            Qb, Kb, VtT, wtr, rsp, tl);
  att_kernel<<<512, 256, 0, stream>>>(Qb, Kb, VtT, tl, AOb, Lv, Eb);
  gemmo_ent_kernel<<<768, 256, 0, stream>>>(AOb, wob, bo, out, Eb, Lv, certainty, outc);
}